// Round 2
// baseline (181.964 us; speedup 1.0000x reference)
//
#include <hip/hip_runtime.h>
#include <cstdint>
#include <cstddef>

// Problem shape (fixed by the reference setup_inputs)
#define MDIM 8192
#define KDIM 2048
#define NDIM 2048
#define QBLK 128
#define KB   (KDIM / QBLK)   // 16
#define NB   (NDIM / QBLK)   // 16

typedef float floatx4 __attribute__((ext_vector_type(4)));
typedef int   int4v   __attribute__((ext_vector_type(4)));
typedef int   int8v   __attribute__((ext_vector_type(8)));

#define AS1 __attribute__((address_space(1)))
#define AS3 __attribute__((address_space(3)))

// ---------------------------------------------------------------------------
// fp8 e4m3fn helpers (software, bit-exact) — used by cold paths + check
// ---------------------------------------------------------------------------
__device__ inline float e4m3_rne(float q) {     // RNE to fp8 grid, |q| <= 448
    float aq = fabsf(q);
    float r;
    if (aq < 0.015625f) {                        // subnormal: grid 2^-9
        r = rintf(aq * 512.0f) * 0.001953125f;
    } else {
        unsigned u = __float_as_uint(aq);
        unsigned rem = u & 0xFFFFFu;
        unsigned base = u & ~0xFFFFFu;
        unsigned inc = (rem > 0x80000u || (rem == 0x80000u && (u & 0x100000u))) ? 0x100000u : 0u;
        r = __uint_as_float(base + inc);
    }
    return q < 0.0f ? -r : r;
}

__device__ inline unsigned e4m3_encode(float r) {  // r exactly on fp8 grid
    unsigned u = __float_as_uint(r);
    unsigned s = (u >> 24) & 0x80u;
    float a = fabsf(r);
    if (a < 0.015625f) return s | (unsigned)(a * 512.0f + 0.25f);
    unsigned e = ((u >> 23) & 0xFFu) - 120u;       // 1..15
    unsigned m = (u >> 20) & 7u;
    return s | (e << 3) | m;
}

__device__ inline float e4m3_decode(unsigned b) {
    unsigned s = b >> 7, e = (b >> 3) & 0xFu, m = b & 7u;
    float v;
    if (e == 0) v = (float)m * 0.001953125f;
    else        v = __uint_as_float((e + 120u) << 23) * (float)(8 + m) * 0.125f;
    return s ? -v : v;
}

__device__ inline int is_expbyte(unsigned b) {   // plausible f32/bf16 hi byte for fp8-exact value
    unsigned e = b & 0x7Fu;
    return (e >= 0x3Bu && e <= 0x43u) || e == 0x00u;
}

// ---------------------------------------------------------------------------
// Workspace layout
//   xq  [M][K]  fp8 bytes            @ 0        (16 MB)
//   wq8 [N][K]  fp8 bytes            @ 16 MB    (4 MB)
//   xs  [M][KB] f32 act scales       @ 20 MB    (512 KB)
//   flag int                         @ 20.5 MB
// ---------------------------------------------------------------------------
#define XQ_OFF  0
#define WQ_OFF  ((size_t)MDIM * KDIM)
#define XS_OFF  (WQ_OFF + (size_t)NDIM * KDIM)
#define FL_OFF  (XS_OFF + (size_t)MDIM * KB * 4)

#define QXB ((MDIM * KB) / 16)         // 8192 act-quant blocks (16 qblocks each)
#define DWB ((NDIM * KDIM / 8) / 256)  // 2048 weight blocks

// ---------------------------------------------------------------------------
// Prep: act quant (8 elems/lane, 16 lanes per (1,128) block) -> fp8 bytes +
// scales via HW v_cvt_pk_fp8_f32 (bit-identical RNE from exact IEEE division);
// weight -> fp8 bytes (delivery format classified per wave via ballot).
// ---------------------------------------------------------------------------
__global__ __launch_bounds__(256) void prep_kernel(const float* __restrict__ x,
                                                   const void* __restrict__ wq,
                                                   unsigned char* __restrict__ xq,
                                                   unsigned char* __restrict__ wq8,
                                                   float* __restrict__ xs,
                                                   int* __restrict__ flag) {
    const int tid = threadIdx.x;
    if (blockIdx.x == 0 && tid == 0) *flag = 0;

    if (blockIdx.x < QXB) {
        // ---- activation quant: one 16-lane group per (1,128) block ----
        const int g = tid >> 4;
        const int l = tid & 15;
        const size_t bi = (size_t)blockIdx.x * 16 + g;   // = m*KB + kb
        const size_t base = bi << 7;

        const float4* xp = (const float4*)(x + base + (size_t)l * 8);
        const float4 v0 = xp[0], v1 = xp[1];
        float a = fmaxf(fmaxf(fmaxf(fabsf(v0.x), fabsf(v0.y)), fmaxf(fabsf(v0.z), fabsf(v0.w))),
                        fmaxf(fmaxf(fabsf(v1.x), fabsf(v1.y)), fmaxf(fabsf(v1.z), fabsf(v1.w))));
        a = fmaxf(a, __shfl_xor(a, 1));
        a = fmaxf(a, __shfl_xor(a, 2));
        a = fmaxf(a, __shfl_xor(a, 4));
        a = fmaxf(a, __shfl_xor(a, 8));

        const float scale = fmaxf(a, 1e-12f) / 448.0f;
        if (l == 0) xs[bi] = scale;

        // exact IEEE divisions (same as reference), HW RNE pack to fp8
        const float q0 = v0.x / scale, q1 = v0.y / scale, q2 = v0.z / scale, q3 = v0.w / scale;
        const float q4 = v1.x / scale, q5 = v1.y / scale, q6 = v1.z / scale, q7 = v1.w / scale;
        int w0 = __builtin_amdgcn_cvt_pk_fp8_f32(q0, q1, 0, false);
        w0 = __builtin_amdgcn_cvt_pk_fp8_f32(q2, q3, w0, true);
        int w1 = __builtin_amdgcn_cvt_pk_fp8_f32(q4, q5, 0, false);
        w1 = __builtin_amdgcn_cvt_pk_fp8_f32(q6, q7, w1, true);
        *(uint2*)(xq + base + (size_t)l * 8) = make_uint2((unsigned)w0, (unsigned)w1);
    } else {
        // ---- weight repack to fp8 bytes ----
        const int lane = tid & 63;
        const unsigned pw = ((const unsigned*)wq)[lane];
        const unsigned long long m3 = __ballot(is_expbyte((pw >> 24) & 0xFFu));
        const unsigned long long m1 = __ballot(((pw >> 8) & 0xFFu) == 0u);
        const int f = (__popcll(m3) >= 56) ? ((__popcll(m1) >= 56) ? 2 : 1) : 0;

        const size_t idx = (size_t)(blockIdx.x - QXB) * 256 + tid;
        const size_t off = idx * 8;

        unsigned lo, hi;
        if (f == 2) {              // float32 upcast delivery
            const float4* p = (const float4*)((const float*)wq + off);
            const float4 a = p[0], b = p[1];
            lo = e4m3_encode(a.x) | (e4m3_encode(a.y) << 8) | (e4m3_encode(a.z) << 16) | (e4m3_encode(a.w) << 24);
            hi = e4m3_encode(b.x) | (e4m3_encode(b.y) << 8) | (e4m3_encode(b.z) << 16) | (e4m3_encode(b.w) << 24);
        } else if (f == 1) {       // bf16 upcast delivery
            const ushort4 h0 = *(const ushort4*)((const unsigned short*)wq + off);
            const ushort4 h1 = *(((const ushort4*)((const unsigned short*)wq + off)) + 1);
            lo = e4m3_encode(__uint_as_float((unsigned)h0.x << 16))
               | (e4m3_encode(__uint_as_float((unsigned)h0.y << 16)) << 8)
               | (e4m3_encode(__uint_as_float((unsigned)h0.z << 16)) << 16)
               | (e4m3_encode(__uint_as_float((unsigned)h0.w << 16)) << 24);
            hi = e4m3_encode(__uint_as_float((unsigned)h1.x << 16))
               | (e4m3_encode(__uint_as_float((unsigned)h1.y << 16)) << 8)
               | (e4m3_encode(__uint_as_float((unsigned)h1.z << 16)) << 16)
               | (e4m3_encode(__uint_as_float((unsigned)h1.w << 16)) << 24);
        } else {                   // already raw fp8 bytes
            const uint2 d = *(const uint2*)((const unsigned char*)wq + off);
            lo = d.x; hi = d.y;
        }
        *(uint2*)(wq8 + off) = make_uint2(lo, hi);
    }
}

// ---------------------------------------------------------------------------
// Primary GEMM: 256x128 tile, 8 waves (4M x 2N, 64x64/wave), MX fp8 K=128.
// T3+T4 structure: each K-tile split into 4 C-quadrant phases, order
// (0,0),(0,1),(1,1),(1,0) so af (and one bf pair) are register-held across
// adjacent phases. Pure tile-level LDS double-buffer; next tile's stage is
// spread 2+2+2 global_load_lds across phases 0-2.  Counted vmcnt ledger
// (per-wave, loads/phase = {2,2,2,0}):
//   end p0: vmcnt(4)  -> B-h1(next) landed before p1 of next tile reads it
//   end p1: vmcnt(4)  -> A-h1(next) landed before p2 of next tile
//   end p3: vmcnt(3)  -> A-h0+B-h0(next) landed before p0 of next tile
// (min in-flight age >= 3 phases; waits precede the barrier so every wave's
//  contribution is drained before anyone reads).  Last tile peeled with
// vmcnt(2)/vmcnt(0).  wsc goes through LDS (swk) so no VMEM op other than the
// staging loads exists in the loop -> vmcnt counts are exact.
// Fragment addressing / swizzle / MFMA identical to the verified kernel.
// ---------------------------------------------------------------------------
__global__ __launch_bounds__(512, 2) void gemm_mx_kernel(const unsigned char* __restrict__ Aq,
                                                         const unsigned char* __restrict__ Bq,
                                                         const float* __restrict__ xs,
                                                         const float* __restrict__ wsc,
                                                         float* __restrict__ C) {
    __shared__ unsigned char sA[2][256 * 128];   // 64 KB
    __shared__ unsigned char sB[2][128 * 128];   // 32 KB
    __shared__ float sxs[KB][256];               // 16 KB transposed act scales
    __shared__ float swk[KB];                    // weight scales for this n-tile

    const int tid  = threadIdx.x;
    const int wave = tid >> 6;
    const int lane = tid & 63;
    const int lrow = lane & 15;
    const int lk   = lane >> 4;            // k-group (32 bytes each)
    const int lk4  = lk * 4;
    const int wm64 = (wave >> 1) * 64;     // wave m-offset (4 waves in M)
    const int wn64 = (wave & 1) * 64;      // wave n-offset (2 waves in N)

    // XCD-grouped bijective tile map: 512 blocks; XCD g gets m-tiles {4g..4g+3}
    // x all 16 n-tiles.
    const int bid   = blockIdx.x;
    const int lid   = ((bid & 7) << 6) | (bid >> 3);
    const int m0    = (lid >> 4) * 256;
    const int ntile = lid & 15;
    const int n0    = ntile * 128;

    // staging geometry: rbase covers rows [0,32)u[64,96); half-tiles add
    // +32*h and (A only) +128*l.  phys chunk tid&7 holds logical (tid&7)^(row&7).
    const int rbase = 64 * (tid >> 8) + ((tid >> 3) & 31);
    const int gck   = (tid & 7) ^ ((tid >> 3) & 7);
    const unsigned char* agp = Aq + (size_t)(m0 + rbase) * KDIM + (size_t)gck * 16;
    const unsigned char* bgp = Bq + (size_t)(n0 + rbase) * KDIM + (size_t)gck * 16;
    const int ldsT = rbase * 128 + (tid & 7) * 16;

#define GL(SRC, DST) __builtin_amdgcn_global_load_lds((const AS1 void*)(SRC), (AS3 void*)(DST), 16, 0, 0)

    // ---- prologue: LDS scale tables first (their result-waits drain before
    // any stage is issued), then tile-0 stages, then counted wait ----
    if (tid < 256) {
        const float4* xp = (const float4*)(xs + (size_t)(m0 + tid) * KB);
#pragma unroll
        for (int q = 0; q < 4; ++q) {
            const float4 v = xp[q];
            sxs[q * 4 + 0][tid] = v.x;
            sxs[q * 4 + 1][tid] = v.y;
            sxs[q * 4 + 2][tid] = v.z;
            sxs[q * 4 + 3][tid] = v.w;
        }
    }
    if (tid < KB) swk[tid] = wsc[ntile * KB + tid];

    GL(agp,                              &sA[0][0] + ldsT);            // A-h0 l0
    GL(agp + (size_t)128 * KDIM,         &sA[0][0] + 16384 + ldsT);    // A-h0 l1
    GL(bgp,                              &sB[0][0] + ldsT);            // B-h0
    GL(bgp + (size_t)32 * KDIM,          &sB[0][0] + 4096 + ldsT);     // B-h1
    GL(agp + (size_t)32 * KDIM,          &sA[0][0] + 4096 + ldsT);     // A-h1 l0
    GL(agp + (size_t)160 * KDIM,         &sA[0][0] + 20480 + ldsT);    // A-h1 l1

    asm volatile("s_waitcnt vmcnt(3) lgkmcnt(0)" ::: "memory");
    asm volatile("s_barrier" ::: "memory");

    floatx4 acc[4][4] = {};
    const floatx4 zero = {0.f, 0.f, 0.f, 0.f};
    int8v af0, af1, bfa, bfb;
    floatx4 cs0, cs1;

#define FRAG(dst, basep, ROW) do {                                              \
    const int _r = (ROW);                                                       \
    const unsigned char* _p = (basep) + _r * 128;                               \
    const int _c0 = (lk * 2) ^ (_r & 7);                                        \
    ((int4v*)&(dst))[0] = *(const int4v*)(_p + _c0 * 16);                       \
    ((int4v*)&(dst))[1] = *(const int4v*)(_p + (_c0 ^ 1) * 16);                 \
} while (0)

#define MM(I, J, AF, BF, CS) do {                                               \
    floatx4 _blk = __builtin_amdgcn_mfma_scale_f32_16x16x128_f8f6f4(            \
        AF, BF, zero, 0, 0, 0, 0x7F7F7F7F, 0, 0x7F7F7F7F);                      \
    acc[I][J] += (CS) * _blk;                                                   \
} while (0)

    const int arA = wm64 + lrow;
    const int arB = wn64 + lrow;

    for (int t = 0; t < KB - 1; ++t) {
        const int cur = t & 1;
        const unsigned char* sAc = &sA[cur][0];
        const unsigned char* sBc = &sB[cur][0];
        unsigned char* sAn = &sA[cur ^ 1][0];
        unsigned char* sBn = &sB[cur ^ 1][0];
        const size_t koff2 = (size_t)(t + 1) * QBLK;
        const float wsk = swk[t];

        // ---- phase 0: (ih0, jh0) ----
        FRAG(af0, sAc, arA);
        FRAG(af1, sAc, arA + 16);
        FRAG(bfa, sBc, arB);
        FRAG(bfb, sBc, arB + 16);
        cs0 = (*(const floatx4*)&sxs[t][wm64 + lk4]) * wsk;
        cs1 = (*(const floatx4*)&sxs[t][wm64 + 16 + lk4]) * wsk;
        GL(agp + koff2,                       sAn + ldsT);           // A-h0 l0
        GL(agp + (size_t)128 * KDIM + koff2,  sAn + 16384 + ldsT);   // A-h0 l1
        asm volatile("s_barrier" ::: "memory");
        __builtin_amdgcn_s_setprio(1);
        MM(0, 0, af0, bfa, cs0); MM(0, 1, af0, bfb, cs0);
        MM(1, 0, af1, bfa, cs1); MM(1, 1, af1, bfb, cs1);
        __builtin_amdgcn_s_setprio(0);
        asm volatile("s_waitcnt vmcnt(4)" ::: "memory");
        asm volatile("s_barrier" ::: "memory");

        // ---- phase 1: (ih0, jh1) — af/cs held ----
        FRAG(bfa, sBc, arB + 32);
        FRAG(bfb, sBc, arB + 48);
        GL(bgp + koff2,                       sBn + ldsT);           // B-h0
        GL(bgp + (size_t)32 * KDIM + koff2,   sBn + 4096 + ldsT);    // B-h1
        asm volatile("s_barrier" ::: "memory");
        __builtin_amdgcn_s_setprio(1);
        MM(0, 2, af0, bfa, cs0); MM(0, 3, af0, bfb, cs0);
        MM(1, 2, af1, bfa, cs1); MM(1, 3, af1, bfb, cs1);
        __builtin_amdgcn_s_setprio(0);
        asm volatile("s_waitcnt vmcnt(4)" ::: "memory");
        asm volatile("s_barrier" ::: "memory");

        // ---- phase 2: (ih1, jh1) — bf held ----
        FRAG(af0, sAc, arA + 32);
        FRAG(af1, sAc, arA + 48);
        cs0 = (*(const floatx4*)&sxs[t][wm64 + 32 + lk4]) * wsk;
        cs1 = (*(const floatx4*)&sxs[t][wm64 + 48 + lk4]) * wsk;
        GL(agp + (size_t)32 * KDIM + koff2,   sAn + 4096 + ldsT);    // A-h1 l0
        GL(agp + (size_t)160 * KDIM + koff2,  sAn + 20480 + ldsT);   // A-h1 l1
        asm volatile("s_barrier" ::: "memory");
        __builtin_amdgcn_s_setprio(1);
        MM(2, 2, af0, bfa, cs0); MM(2, 3, af0, bfb, cs0);
        MM(3, 2, af1, bfa, cs1); MM(3, 3, af1, bfb, cs1);
        __builtin_amdgcn_s_setprio(0);
        asm volatile("s_barrier" ::: "memory");

        // ---- phase 3: (ih1, jh0) — af/cs held, B-h0 re-read ----
        FRAG(bfa, sBc, arB);
        FRAG(bfb, sBc, arB + 16);
        asm volatile("s_barrier" ::: "memory");
        __builtin_amdgcn_s_setprio(1);
        MM(2, 0, af0, bfa, cs0); MM(2, 1, af0, bfb, cs0);
        MM(3, 0, af1, bfa, cs1); MM(3, 1, af1, bfb, cs1);
        __builtin_amdgcn_s_setprio(0);
        asm volatile("s_waitcnt vmcnt(3)" ::: "memory");
        asm volatile("s_barrier" ::: "memory");
    }

    // ---- peeled last tile (t = KB-1, buffer 1): no stages ----
    {
        const int t = KB - 1;
        const unsigned char* sAc = &sA[1][0];
        const unsigned char* sBc = &sB[1][0];
        const float wsk = swk[t];

        FRAG(af0, sAc, arA);
        FRAG(af1, sAc, arA + 16);
        FRAG(bfa, sBc, arB);
        FRAG(bfb, sBc, arB + 16);
        cs0 = (*(const floatx4*)&sxs[t][wm64 + lk4]) * wsk;
        cs1 = (*(const floatx4*)&sxs[t][wm64 + 16 + lk4]) * wsk;
        MM(0, 0, af0, bfa, cs0); MM(0, 1, af0, bfb, cs0);
        MM(1, 0, af1, bfa, cs1); MM(1, 1, af1, bfb, cs1);
        asm volatile("s_waitcnt vmcnt(2)" ::: "memory");  // B-h1 landed
        asm volatile("s_barrier" ::: "memory");

        FRAG(bfa, sBc, arB + 32);
        FRAG(bfb, sBc, arB + 48);
        MM(0, 2, af0, bfa, cs0); MM(0, 3, af0, bfb, cs0);
        MM(1, 2, af1, bfa, cs1); MM(1, 3, af1, bfb, cs1);
        asm volatile("s_waitcnt vmcnt(0)" ::: "memory");  // A-h1 landed
        asm volatile("s_barrier" ::: "memory");

        FRAG(af0, sAc, arA + 32);
        FRAG(af1, sAc, arA + 48);
        cs0 = (*(const floatx4*)&sxs[t][wm64 + 32 + lk4]) * wsk;
        cs1 = (*(const floatx4*)&sxs[t][wm64 + 48 + lk4]) * wsk;
        MM(2, 2, af0, bfa, cs0); MM(2, 3, af0, bfb, cs0);
        MM(3, 2, af1, bfa, cs1); MM(3, 3, af1, bfb, cs1);

        FRAG(bfa, sBc, arB);
        FRAG(bfb, sBc, arB + 16);
        MM(2, 0, af0, bfa, cs0); MM(2, 1, af0, bfb, cs0);
        MM(3, 0, af1, bfa, cs1); MM(3, 1, af1, bfb, cs1);
    }
#undef FRAG
#undef MM
#undef GL

    // Epilogue: col = lane&15, row = lk*4 + r
#pragma unroll
    for (int i = 0; i < 4; ++i) {
        const int row0 = m0 + wm64 + i * 16 + lk4;
#pragma unroll
        for (int r = 0; r < 4; ++r) {
            float* cp = C + (size_t)(row0 + r) * NDIM + n0 + wn64 + lrow;
#pragma unroll
            for (int j = 0; j < 4; ++j)
                cp[j * 16] = acc[i][j][r];
        }
    }
}

// ---------------------------------------------------------------------------
// Check: recompute 64 sampled outputs exactly from the quantized bytes; set
// flag if the MX GEMM result deviates (NaN-safe compare).
// ---------------------------------------------------------------------------
__global__ __launch_bounds__(256) void check_kernel(const unsigned char* __restrict__ xq,
                                                    const unsigned char* __restrict__ wq8,
                                                    const float* __restrict__ xs,
                                                    const float* __restrict__ wsc,
                                                    const float* __restrict__ y,
                                                    int* __restrict__ flag) {
    const int s = blockIdx.x;
    const int m = (s * 1237 + 11) & (MDIM - 1);
    const int n = (s * 389 + 7) & (NDIM - 1);
    const int tid = threadIdx.x;
    const int k0 = tid * 8;
    const int kb = k0 >> 7;

    const unsigned char* xp = xq + (size_t)m * KDIM + k0;
    const unsigned char* wp = wq8 + (size_t)n * KDIM + k0;
    float dot = 0.f;
#pragma unroll
    for (int i = 0; i < 8; ++i)
        dot += e4m3_decode(xp[i]) * e4m3_decode(wp[i]);
    float part = dot * xs[m * KB + kb] * wsc[(n >> 7) * KB + kb];

#pragma unroll
    for (int o = 32; o > 0; o >>= 1) part += __shfl_down(part, o);
    __shared__ float wsum[4];
    if ((tid & 63) == 0) wsum[tid >> 6] = part;
    __syncthreads();
    if (tid == 0) {
        const float tot = wsum[0] + wsum[1] + wsum[2] + wsum[3];
        const float d = tot - y[(size_t)m * NDIM + n];
        if (!(fabsf(d) <= 0.05f)) atomicOr(flag, 1);
    }
}

// ---------------------------------------------------------------------------
// Fallback GEMM (flag-guarded): non-scaled mfma_f32_16x16x32_fp8_fp8 (m145-
// verified k-geometry) + identical VALU scale fixup. Only runs if the MX
// layout check failed. Unchanged from the verified kernel.
// ---------------------------------------------------------------------------
__global__ __launch_bounds__(256, 2) void gemm_fb_kernel(const unsigned char* __restrict__ Aq,
                                                         const unsigned char* __restrict__ Bq,
                                                         const float* __restrict__ xs,
                                                         const float* __restrict__ wsc,
                                                         float* __restrict__ C,
                                                         const int* __restrict__ flag) {
    if (*flag == 0) return;

    __shared__ unsigned char sA[128 * 128];
    __shared__ unsigned char sB[128 * 128];

    const int tid  = threadIdx.x;
    const int wave = tid >> 6;
    const int lane = tid & 63;
    const int lrow = lane & 15;
    const int lk   = lane >> 4;
    const int wm   = (wave & 1) * 64;
    const int wn   = (wave >> 1) * 64;
    const int m0   = blockIdx.y * 128;
    const int n0   = blockIdx.x * 128;
    const int nb   = n0 >> 7;

    const int srow = tid >> 3;
    const int gck  = (tid & 7) ^ (srow & 7);
    const unsigned char* agp = Aq + (size_t)(m0 + srow) * KDIM + gck * 16;
    const unsigned char* bgp = Bq + (size_t)(n0 + srow) * KDIM + gck * 16;

    floatx4 acc[4][4] = {};

    for (int kb = 0; kb < KB; ++kb) {
        const size_t koff = (size_t)kb * QBLK;
        __syncthreads();
#pragma unroll
        for (int it = 0; it < 4; ++it)
            __builtin_amdgcn_global_load_lds(
                (const AS1 void*)(agp + (size_t)(it * 32) * KDIM + koff),
                (AS3 void*)(sA + tid * 16 + it * 4096), 16, 0, 0);
#pragma unroll
        for (int it = 0; it < 4; ++it)
            __builtin_amdgcn_global_load_lds(
                (const AS1 void*)(bgp + (size_t)(it * 32) * KDIM + koff),
                (AS3 void*)(sB + tid * 16 + it * 4096), 16, 0, 0);
        __syncthreads();

        floatx4 blk[4][4] = {};
#pragma unroll
        for (int ks = 0; ks < 4; ++ks) {        // K = 32 per MFMA
            long a8[4], b8[4];
            const int lc = ks * 2 + (lk >> 1);  // logical chunk of this 8B frag
            const int bo = (lk & 1) * 8;        // byte offset within chunk
#pragma unroll
            for (int i = 0; i < 4; ++i) {
                const int Ra = wm + i * 16 + lrow;
                a8[i] = *(const long*)(sA + Ra * 128 + (lc ^ (Ra & 7)) * 16 + bo);
                const int Rb = wn + i * 16 + lrow;
                b8[i] = *(const long*)(sB + Rb * 128 + (lc ^ (Rb & 7)) * 16 + bo);
            }
#pragma unroll
            for (int i = 0; i < 4; ++i)
#pragma unroll
                for (int j = 0; j < 4; ++j)
                    blk[i][j] = __builtin_amdgcn_mfma_f32_16x16x32_fp8_fp8(a8[i], b8[j], blk[i][j], 0, 0, 0);
        }

        const float wsk = wsc[nb * KB + kb];
#pragma unroll
        for (int i = 0; i < 4; ++i) {
            float cs[4];
#pragma unroll
            for (int r = 0; r < 4; ++r)
                cs[r] = xs[(size_t)(m0 + wm + i * 16 + lk * 4 + r) * KB + kb] * wsk;
#pragma unroll
            for (int j = 0; j < 4; ++j)
#pragma unroll
                for (int r = 0; r < 4; ++r)
                    acc[i][j][r] += cs[r] * blk[i][j][r];
        }
    }

#pragma unroll
    for (int i = 0; i < 4; ++i) {
        const int row0 = m0 + wm + i * 16 + lk * 4;
#pragma unroll
        for (int r = 0; r < 4; ++r) {
            float* cp = C + (size_t)(row0 + r) * NDIM + n0 + wn + lrow;
#pragma unroll
            for (int j = 0; j < 4; ++j)
                cp[j * 16] = acc[i][j][r];
        }
    }
}

// ---------------------------------------------------------------------------
extern "C" void kernel_launch(void* const* d_in, const int* in_sizes, int n_in,
                              void* d_out, int out_size, void* d_ws, size_t ws_size,
                              hipStream_t stream) {
    const float* x      = (const float*)d_in[0];
    const void* wq      = d_in[1];
    const float* wscale = (const float*)d_in[2];
    float* y            = (float*)d_out;

    unsigned char* xq  = (unsigned char*)d_ws + XQ_OFF;
    unsigned char* wq8 = (unsigned char*)d_ws + WQ_OFF;
    float* xs          = (float*)((unsigned char*)d_ws + XS_OFF);
    int* flag          = (int*)((unsigned char*)d_ws + FL_OFF);

    prep_kernel<<<QXB + DWB, 256, 0, stream>>>(x, wq, xq, wq8, xs, flag);
    gemm_mx_kernel<<<(MDIM / 256) * (NDIM / 128), 512, 0, stream>>>(xq, wq8, xs, wscale, y);
    check_kernel<<<64, 256, 0, stream>>>(xq, wq8, xs, wscale, y, flag);
    gemm_fb_kernel<<<dim3(NDIM / 128, MDIM / 128), 256, 0, stream>>>(xq, wq8, xs, wscale, y, flag);
}